// Round 9
// baseline (208.812 us; speedup 1.0000x reference)
//
#include <hip/hip_runtime.h>
#include <hip/hip_bf16.h>
#include <cmath>

#define ALPHA 1.702f
#define LIMIT 7.0f

constexpr int B = 2, S = 1024, H = 768, E = 8, I = 768;
constexpr int T = B * S;          // 2048 tokens
constexpr int TWO_I = 2 * I;      // 1536
constexpr int CAP = T;            // per-expert row capacity
constexpr int NT1 = I / 64;       // 12 n-tiles (gemm1)
constexpr int NT2 = H / 64;       // 12 n-tiles (gemm2)
constexpr int MT = CAP / 128;     // 16 m-tiles

constexpr int RTR_BLKS = 64;
constexpr int WGU_TILES = E * (TWO_I / 64) * (H / 64);  // 2304
constexpr int WD_TILES  = E * (H / 64) * (H / 64);      // 1152
constexpr int PRE_BLKS = RTR_BLKS + WGU_TILES;          // 2368
constexpr int G1_BLKS = MT * E * NT1;                   // 1536
constexpr int K1_BLKS = G1_BLKS + WD_TILES;             // 2688
constexpr int G2_BLKS = MT * E * NT2;                   // 1536
constexpr int RED_BLKS = (T * H / 4) / 256;             // 1536

typedef __attribute__((ext_vector_type(8))) short short8;
typedef __attribute__((ext_vector_type(4))) float floatx4;

__device__ __forceinline__ unsigned short f2bf(float v) {
  __hip_bfloat16 h = __float2bfloat16(v);
  return *reinterpret_cast<unsigned short*>(&h);
}

// 64x64 fp32->bf16 transpose tile via LDS (R1-proven body).
__device__ __forceinline__ void transpose_tile(
    const float* __restrict__ in, unsigned short* __restrict__ outw,
    int N, int n0, int k0, float (*tile)[65], int tid) {
  constexpr int K = 768;
  int jr = tid & 15, r0 = tid >> 4;
#pragma unroll
  for (int p = 0; p < 4; p++) {
    int k = r0 + p * 16;
    float4 v = *(const float4*)(in + (size_t)(k0 + k) * N + n0 + jr * 4);
    tile[k][jr * 4 + 0] = v.x;
    tile[k][jr * 4 + 1] = v.y;
    tile[k][jr * 4 + 2] = v.z;
    tile[k][jr * 4 + 3] = v.w;
  }
  __syncthreads();
#pragma unroll
  for (int p = 0; p < 4; p++) {
    int n = r0 + p * 16;
    ushort4 o;
    o.x = f2bf(tile[jr * 4 + 0][n]);
    o.y = f2bf(tile[jr * 4 + 1][n]);
    o.z = f2bf(tile[jr * 4 + 2][n]);
    o.w = f2bf(tile[jr * 4 + 3][n]);
    *(ushort4*)(outw + (size_t)(n0 + n) * K + k0 + jr * 4) = o;
  }
}

// ---------------------------------------------------------------------------
// K0: router (+assignment, xb cast) and Wgu transpose in ONE launch.
// (byte-identical to R8)
// ---------------------------------------------------------------------------
__global__ __launch_bounds__(256) void pre_router_wgu(
    const float* __restrict__ x, const float* __restrict__ Wr,
    const float* __restrict__ br, const float* __restrict__ Wgu,
    unsigned short* __restrict__ Wgt, unsigned short* __restrict__ xb,
    int* __restrict__ e_cnt, int* __restrict__ row_token,
    float* __restrict__ row_w) {
  int bid = blockIdx.x;
  int tid = threadIdx.x;

  if (bid < RTR_BLKS) {
    __shared__ int cnt_s[E];
    __shared__ int base_s[E];
    __shared__ int tok_e[E][64];
    __shared__ float wv_e[E][64];

    if (tid < E) cnt_s[tid] = 0;
    __syncthreads();

    int wave = tid >> 6;
    int lane = tid & 63;

    for (int tt = 0; tt < 8; tt++) {
      int t = bid * 32 + wave * 8 + tt;
      const float* xr = x + (size_t)t * H;

      float acc[E];
#pragma unroll
      for (int e = 0; e < E; e++) acc[e] = 0.0f;

#pragma unroll
      for (int it = 0; it < 3; it++) {
        int h4 = it * 64 + lane;
        float4 xv = *(const float4*)(xr + (size_t)h4 * 4);
        ushort4 xo;
        xo.x = f2bf(xv.x);
        xo.y = f2bf(xv.y);
        xo.z = f2bf(xv.z);
        xo.w = f2bf(xv.w);
        *(ushort4*)(xb + (size_t)t * H + (size_t)h4 * 4) = xo;
        const float* wrow = Wr + (size_t)h4 * 4 * E;
        float xs[4] = {xv.x, xv.y, xv.z, xv.w};
#pragma unroll
        for (int j = 0; j < 4; j++)
#pragma unroll
          for (int e = 0; e < E; e++) acc[e] += xs[j] * wrow[j * E + e];
      }
#pragma unroll
      for (int e = 0; e < E; e++) {
        float v = acc[e];
        for (int off = 32; off > 0; off >>= 1) v += __shfl_down(v, off, 64);
        acc[e] = v;
      }
      if (lane == 0) {
        float logits[E];
#pragma unroll
        for (int e = 0; e < E; e++) logits[e] = acc[e] + br[e];
        int i0 = 0;
        float v0 = logits[0];
#pragma unroll
        for (int e = 1; e < E; e++)
          if (logits[e] > v0) { v0 = logits[e]; i0 = e; }
        int i1 = -1;
        float v1 = -INFINITY;
#pragma unroll
        for (int e = 0; e < E; e++) {
          if (e == i0) continue;
          if (logits[e] > v1) { v1 = logits[e]; i1 = e; }
        }
        float s1 = __expf(v1 - v0);
        float denom = 1.0f + s1;
        int p0 = atomicAdd(&cnt_s[i0], 1);
        tok_e[i0][p0] = t * 2 + 0;       // slot 0
        wv_e[i0][p0] = 1.0f / denom;
        int p1 = atomicAdd(&cnt_s[i1], 1);
        tok_e[i1][p1] = t * 2 + 1;       // slot 1
        wv_e[i1][p1] = s1 / denom;
      }
    }
    __syncthreads();
    if (tid < E) base_s[tid] = atomicAdd(&e_cnt[tid], cnt_s[tid]);
    __syncthreads();
#pragma unroll
    for (int e = 0; e < E; e++) {
      int c = cnt_s[e], b0 = base_s[e];
      for (int j = tid; j < c; j += 256) {
        row_token[e * CAP + b0 + j] = tok_e[e][j];
        row_w[e * CAP + b0 + j] = wv_e[e][j];
      }
    }
    return;
  }

  // Wgu transpose tiles
  __shared__ float tile[64][65];
  int q = bid - RTR_BLKS;
  int e = q / 288, rem = q % 288;
  int n0 = (rem % 24) * 64;
  int k0 = (rem / 24) * 64;
  transpose_tile(Wgu + (size_t)e * H * TWO_I, Wgt + (size_t)e * TWO_I * H,
                 TWO_I, n0, k0, tile, tid);
}

// ---------------------------------------------------------------------------
// K1: gemm1, PURE-REGISTER operands (no LDS staging, no barriers, no asm).
// Both operands are L2-hot (B-slab/XCD = 2.8 MB via bid%8 affinity; xb 3.1 MB
// total). Each lane loads its MFMA fragments directly: 16B short8 loads,
// explicit 2-deep register prefetch, all indices static. Compiler inserts
// exact s_waitcnt for register deps — no inter-wave sync exists at all.
// LDS = tok[128] + transpose tile union -> ~17 KB -> occupancy is wave-bound
// (8 blocks/CU), waves never barrier-locked.
// Wd-transpose blocks appended as in R3/R8.
// ---------------------------------------------------------------------------
__global__ __launch_bounds__(256) void gemm_gu_wdT(
    const unsigned short* __restrict__ xb, const unsigned short* __restrict__ Wgt,
    const float* __restrict__ bgu, const int* __restrict__ e_cnt,
    const int* __restrict__ row_token, unsigned short* __restrict__ act,
    const float* __restrict__ Wd, unsigned short* __restrict__ Wdt) {
  __shared__ float tile[64][65];
  __shared__ int tok[128];
  int bid = blockIdx.x;
  int tid = threadIdx.x;

  if (bid >= G1_BLKS) {
    int q = bid - G1_BLKS;
    int e = q / 144, rem = q % 144;
    int n0 = (rem % 12) * 64;
    int k0 = (rem / 12) * 64;
    transpose_tile(Wd + (size_t)e * H * I, Wdt + (size_t)e * H * I,
                   H, n0, k0, tile, tid);
    return;
  }

  int g = bid % (E * NT1);       // (e*12 + n), fixed XCD = g%8
  int mt = bid / (E * NT1);
  int e = g / NT1;
  int n0 = (g % NT1) * 64;
  int cnt = e_cnt[e];
  int m0 = mt * 128;
  if (m0 >= cnt) return;
  int start = e * CAP;
  const unsigned short* Wg = Wgt + (size_t)e * TWO_I * H;  // [f][h]
  const float* bias = bgu + (size_t)e * TWO_I;

  if (tid < 128) {
    int m = m0 + tid;
    tok[tid] = row_token[start + ((m < cnt) ? m : (cnt - 1))];
  }
  __syncthreads();

  int lane = tid & 63;
  int wave = tid >> 6;
  int quad = lane >> 4;
  int lrow = lane & 15;
  int wm = (wave >> 1) * 64;
  int wn = (wave & 1) * 32;

  // Per-lane fragment base pointers (16B chunk at quad*8 within each K-step).
  const unsigned short* aP[4];
#pragma unroll
  for (int ti = 0; ti < 4; ti++)
    aP[ti] = xb + (size_t)(tok[wm + ti * 16 + lrow] >> 1) * H + quad * 8;
  const unsigned short *gP[2], *uP[2];
#pragma unroll
  for (int tj = 0; tj < 2; tj++) {
    int r = n0 + wn + tj * 16 + lrow;
    gP[tj] = Wg + (size_t)r * H + quad * 8;
    uP[tj] = gP[tj] + (size_t)I * H;
  }

  float bgv[2], buv[2];
#pragma unroll
  for (int tj = 0; tj < 2; tj++) {
    int ncol = n0 + wn + tj * 16 + lrow;
    bgv[tj] = bias[ncol];
    buv[tj] = bias[I + ncol];
  }

  floatx4 accg[4][2], accu[4][2];
#pragma unroll
  for (int i = 0; i < 4; i++)
#pragma unroll
    for (int j = 0; j < 2; j++) {
      accg[i][j] = floatx4{0.f, 0.f, 0.f, 0.f};
      accu[i][j] = floatx4{0.f, 0.f, 0.f, 0.f};
    }

  constexpr int NK = H / 32;  // 24 K-steps of 32

  short8 a0[4], g0[2], u0[2], a1[4], g1[2], u1[2];

#define LD_FRAG(kk, A, G, U)                                         \
  {                                                                  \
    _Pragma("unroll") for (int ti = 0; ti < 4; ti++)                 \
        A[ti] = *(const short8*)(aP[ti] + (kk)*32);                  \
    _Pragma("unroll") for (int tj = 0; tj < 2; tj++) {               \
      G[tj] = *(const short8*)(gP[tj] + (kk)*32);                    \
      U[tj] = *(const short8*)(uP[tj] + (kk)*32);                    \
    }                                                                \
  }
#define MFMA_STEP(A, G, U)                                           \
  {                                                                  \
    _Pragma("unroll") for (int ti = 0; ti < 4; ti++)                 \
        _Pragma("unroll") for (int tj = 0; tj < 2; tj++) {           \
      accg[ti][tj] = __builtin_amdgcn_mfma_f32_16x16x32_bf16(        \
          A[ti], G[tj], accg[ti][tj], 0, 0, 0);                      \
      accu[ti][tj] = __builtin_amdgcn_mfma_f32_16x16x32_bf16(        \
          A[ti], U[tj], accu[ti][tj], 0, 0, 0);                      \
    }                                                                \
  }

  LD_FRAG(0, a0, g0, u0);
  for (int k = 0; k < NK; k += 2) {
    LD_FRAG(k + 1, a1, g1, u1);
    MFMA_STEP(a0, g0, u0);
    if (k + 2 < NK) LD_FRAG(k + 2, a0, g0, u0);
    MFMA_STEP(a1, g1, u1);
  }
#undef LD_FRAG
#undef MFMA_STEP

#pragma unroll
  for (int ti = 0; ti < 4; ti++) {
#pragma unroll
    for (int tj = 0; tj < 2; tj++) {
      int ncol = n0 + wn + tj * 16 + lrow;
#pragma unroll
      for (int r = 0; r < 4; r++) {
        int m = m0 + wm + ti * 16 + quad * 4 + r;
        if (m < cnt) {
          float gg = accg[ti][tj][r] + bgv[tj];
          float u = accu[ti][tj][r] + buv[tj];
          gg = fminf(gg, LIMIT);
          u = fmaxf(fminf(u, LIMIT), -LIMIT);
          float glu = gg / (1.0f + __expf(-ALPHA * gg));
          act[(size_t)(start + m) * I + ncol] = f2bf((u + 1.0f) * glu);
        }
      }
    }
  }
}

// ---------------------------------------------------------------------------
// GEMM2: pure-register operands, same scheme. down[t*2+slot][H] plain stores
// (R8-proven no-atomic scatter), reduce kernel sums the two slots.
// ---------------------------------------------------------------------------
__global__ __launch_bounds__(256) void gemm_down_mfma(
    const unsigned short* __restrict__ act, const unsigned short* __restrict__ Wdt,
    const float* __restrict__ bd, const int* __restrict__ e_cnt,
    const int* __restrict__ row_token, const float* __restrict__ row_w,
    float* __restrict__ down) {
  __shared__ int tok[128];
  __shared__ float wts[128];
  int bid = blockIdx.x;
  int tid = threadIdx.x;

  int g = bid % (E * NT2);
  int mt = bid / (E * NT2);
  int e = g / NT2;
  int n0 = (g % NT2) * 64;
  int cnt = e_cnt[e];
  int m0 = mt * 128;
  if (m0 >= cnt) return;
  int start = e * CAP;
  const unsigned short* Wd = Wdt + (size_t)e * H * I;  // [h][i]
  const float* bias = bd + (size_t)e * H;

  if (tid < 128) {
    int m = m0 + tid;
    int mm = (m < cnt) ? m : (cnt - 1);
    tok[tid] = row_token[start + mm];
    wts[tid] = row_w[start + mm];
  }
  __syncthreads();

  int lane = tid & 63;
  int wave = tid >> 6;
  int quad = lane >> 4;
  int lrow = lane & 15;
  int wm = (wave >> 1) * 64;
  int wn = (wave & 1) * 32;

  const unsigned short* aP[4];
#pragma unroll
  for (int ti = 0; ti < 4; ti++) {
    int gm = m0 + wm + ti * 16 + lrow;
    int mm = (gm < cnt) ? gm : (cnt - 1);
    aP[ti] = act + (size_t)(start + mm) * I + quad * 8;
  }
  const unsigned short* bP[2];
#pragma unroll
  for (int tj = 0; tj < 2; tj++) {
    int r = n0 + wn + tj * 16 + lrow;
    bP[tj] = Wd + (size_t)r * I + quad * 8;
  }

  float bdv[2];
#pragma unroll
  for (int tj = 0; tj < 2; tj++) bdv[tj] = bias[n0 + wn + tj * 16 + lrow];

  floatx4 acc[4][2];
#pragma unroll
  for (int i = 0; i < 4; i++)
#pragma unroll
    for (int j = 0; j < 2; j++) acc[i][j] = floatx4{0.f, 0.f, 0.f, 0.f};

  constexpr int NK = I / 32;  // 24

  short8 a0[4], b0[2], a1[4], b1[2];

#define LD_FRAG2(kk, A, Bv)                                          \
  {                                                                  \
    _Pragma("unroll") for (int ti = 0; ti < 4; ti++)                 \
        A[ti] = *(const short8*)(aP[ti] + (kk)*32);                  \
    _Pragma("unroll") for (int tj = 0; tj < 2; tj++)                 \
        Bv[tj] = *(const short8*)(bP[tj] + (kk)*32);                 \
  }
#define MFMA_STEP2(A, Bv)                                            \
  {                                                                  \
    _Pragma("unroll") for (int ti = 0; ti < 4; ti++)                 \
        _Pragma("unroll") for (int tj = 0; tj < 2; tj++)             \
            acc[ti][tj] = __builtin_amdgcn_mfma_f32_16x16x32_bf16(   \
                A[ti], Bv[tj], acc[ti][tj], 0, 0, 0);                \
  }

  LD_FRAG2(0, a0, b0);
  for (int k = 0; k < NK; k += 2) {
    LD_FRAG2(k + 1, a1, b1);
    MFMA_STEP2(a0, b0);
    if (k + 2 < NK) LD_FRAG2(k + 2, a0, b0);
    MFMA_STEP2(a1, b1);
  }
#undef LD_FRAG2
#undef MFMA_STEP2

#pragma unroll
  for (int ti = 0; ti < 4; ti++) {
#pragma unroll
    for (int tj = 0; tj < 2; tj++) {
      int ncol = n0 + wn + tj * 16 + lrow;
#pragma unroll
      for (int r = 0; r < 4; r++) {
        int ml = wm + ti * 16 + quad * 4 + r;
        int m = m0 + ml;
        if (m < cnt) {
          down[(size_t)tok[ml] * H + ncol] =
              wts[ml] * (acc[ti][tj][r] + bdv[tj]);
        }
      }
    }
  }
}

// ---------------------------------------------------------------------------
// Reduce: out[t][h] = down[t][0][h] + down[t][1][h]. (byte-identical to R8)
// ---------------------------------------------------------------------------
__global__ __launch_bounds__(256) void reduce_out(
    const float* __restrict__ down, float* __restrict__ out) {
  int i4 = blockIdx.x * 256 + threadIdx.x;  // 0 .. T*H/4-1
  int t = i4 / (H / 4);
  int c = i4 % (H / 4);
  const float4* d0 = (const float4*)(down + (size_t)(2 * t) * H) + c;
  const float4* d1 = (const float4*)(down + (size_t)(2 * t + 1) * H) + c;
  float4 a = *d0, b = *d1;
  float4 r = {a.x + b.x, a.y + b.y, a.z + b.z, a.w + b.w};
  ((float4*)(out + (size_t)t * H))[c] = r;
}

// ---------------------------------------------------------------------------
extern "C" void kernel_launch(void* const* d_in, const int* in_sizes, int n_in,
                              void* d_out, int out_size, void* d_ws,
                              size_t ws_size, hipStream_t stream) {
  const float* x   = (const float*)d_in[0];
  const float* Wr  = (const float*)d_in[1];
  const float* br  = (const float*)d_in[2];
  const float* Wgu = (const float*)d_in[3];
  const float* bgu = (const float*)d_in[4];
  const float* Wd  = (const float*)d_in[5];
  const float* bd  = (const float*)d_in[6];
  float* out = (float*)d_out;

  char* w = (char*)d_ws;
  int* e_cnt = (int*)w;       w += 16 * sizeof(int);
  int* row_token = (int*)w;   w += (size_t)E * CAP * sizeof(int);
  float* row_w = (float*)w;   w += (size_t)E * CAP * sizeof(float);
  unsigned short* xb  = (unsigned short*)w; w += (size_t)T * H * 2;         // 3.1 MB
  unsigned short* Wgt = (unsigned short*)w; w += (size_t)E * TWO_I * H * 2; // 18.9 MB
  unsigned short* Wdt = (unsigned short*)w; w += (size_t)E * H * I * 2;     // 9.4 MB
  unsigned short* act = (unsigned short*)w; w += (size_t)E * CAP * I * 2;   // 25.2 MB
  float* down = (float*)w;    w += (size_t)T * 2 * H * sizeof(float);       // 12.6 MB

  hipMemsetAsync(e_cnt, 0, 16 * sizeof(int), stream);
  pre_router_wgu<<<PRE_BLKS, 256, 0, stream>>>(
      x, Wr, br, Wgu, Wgt, xb, e_cnt, row_token, row_w);
  gemm_gu_wdT<<<K1_BLKS, 256, 0, stream>>>(
      xb, Wgt, bgu, e_cnt, row_token, act, Wd, Wdt);
  gemm_down_mfma<<<G2_BLKS, 256, 0, stream>>>(
      act, Wdt, bd, e_cnt, row_token, row_w, down);
  reduce_out<<<RED_BLKS, 256, 0, stream>>>(down, out);
}

// Round 10
// 161.822 us; speedup vs baseline: 1.2904x; 1.2904x over previous
//
#include <hip/hip_runtime.h>
#include <hip/hip_bf16.h>
#include <cmath>

#define ALPHA 1.702f
#define LIMIT 7.0f

constexpr int B = 2, S = 1024, H = 768, E = 8, I = 768;
constexpr int T = B * S;          // 2048 tokens
constexpr int TWO_I = 2 * I;      // 1536
constexpr int CAP = T;            // per-expert row capacity
constexpr int NT1 = I / 64;       // 12 n-tiles (gemm1)
constexpr int NT2 = H / 64;       // 12 n-tiles (gemm2)
constexpr int MT = CAP / 128;     // 16 m-tiles
constexpr int KH = I / 2;         // 384: split-K half for gemm2

constexpr int RTR_BLKS = 128;     // 16 tokens per block (4 waves x 4)
constexpr int WGU_TILES = E * (TWO_I / 64) * (H / 64);  // 2304
constexpr int WD_TILES  = E * (H / 64) * (H / 64);      // 1152
constexpr int PRE_BLKS = RTR_BLKS + WGU_TILES + WD_TILES;  // 3584
constexpr int G1_BLKS = MT * E * NT1;                   // 1536
constexpr int G2_BLKS = 2 * MT * E * NT2;               // 3072 (x2 split-K)
constexpr int RED_BLKS = (T * H / 4) / 256;             // 1536

typedef __attribute__((ext_vector_type(8))) short short8;
typedef __attribute__((ext_vector_type(4))) float floatx4;

__device__ __forceinline__ unsigned short f2bf(float v) {
  __hip_bfloat16 h = __float2bfloat16(v);
  return *reinterpret_cast<unsigned short*>(&h);
}

// async global->LDS, 16B per lane. LDS dst is wave-uniform base + lane*16.
__device__ __forceinline__ void g2l16(const void* g, void* l) {
  __builtin_amdgcn_global_load_lds(
      (const __attribute__((address_space(1))) void*)g,
      (__attribute__((address_space(3))) void*)l, 16, 0, 0);
}

// 64x64 fp32->bf16 transpose tile via LDS (R1-proven body).
__device__ __forceinline__ void transpose_tile(
    const float* __restrict__ in, unsigned short* __restrict__ outw,
    int N, int n0, int k0, float (*tile)[65], int tid) {
  constexpr int K = 768;
  int jr = tid & 15, r0 = tid >> 4;
#pragma unroll
  for (int p = 0; p < 4; p++) {
    int k = r0 + p * 16;
    float4 v = *(const float4*)(in + (size_t)(k0 + k) * N + n0 + jr * 4);
    tile[k][jr * 4 + 0] = v.x;
    tile[k][jr * 4 + 1] = v.y;
    tile[k][jr * 4 + 2] = v.z;
    tile[k][jr * 4 + 3] = v.w;
  }
  __syncthreads();
#pragma unroll
  for (int p = 0; p < 4; p++) {
    int n = r0 + p * 16;
    ushort4 o;
    o.x = f2bf(tile[jr * 4 + 0][n]);
    o.y = f2bf(tile[jr * 4 + 1][n]);
    o.z = f2bf(tile[jr * 4 + 2][n]);
    o.w = f2bf(tile[jr * 4 + 3][n]);
    *(ushort4*)(outw + (size_t)(n0 + n) * K + k0 + jr * 4) = o;
  }
}

// ---------------------------------------------------------------------------
// K0: router (128 blocks x 16 tokens — halved serial chain) + BOTH weight
// transposes (Wd transpose depends on nothing; it fills the router tail here
// instead of padding the gemm1 launch).
// row_token encodes t*2+slot (R8-proven no-atomic scatter downstream).
// ---------------------------------------------------------------------------
__global__ __launch_bounds__(256) void pre_all(
    const float* __restrict__ x, const float* __restrict__ Wr,
    const float* __restrict__ br, const float* __restrict__ Wgu,
    const float* __restrict__ Wd, unsigned short* __restrict__ Wgt,
    unsigned short* __restrict__ Wdt, unsigned short* __restrict__ xb,
    int* __restrict__ e_cnt, int* __restrict__ row_token,
    float* __restrict__ row_w) {
  int bid = blockIdx.x;
  int tid = threadIdx.x;

  if (bid < RTR_BLKS) {
    __shared__ int cnt_s[E];
    __shared__ int base_s[E];
    __shared__ int tok_e[E][32];   // 16 tokens x 2 slots max
    __shared__ float wv_e[E][32];

    if (tid < E) cnt_s[tid] = 0;
    __syncthreads();

    int wave = tid >> 6;
    int lane = tid & 63;

    for (int tt = 0; tt < 4; tt++) {
      int t = bid * 16 + wave * 4 + tt;   // < 2048
      const float* xr = x + (size_t)t * H;

      float acc[E];
#pragma unroll
      for (int e = 0; e < E; e++) acc[e] = 0.0f;

#pragma unroll
      for (int it = 0; it < 3; it++) {
        int h4 = it * 64 + lane;
        float4 xv = *(const float4*)(xr + (size_t)h4 * 4);
        ushort4 xo;
        xo.x = f2bf(xv.x);
        xo.y = f2bf(xv.y);
        xo.z = f2bf(xv.z);
        xo.w = f2bf(xv.w);
        *(ushort4*)(xb + (size_t)t * H + (size_t)h4 * 4) = xo;
        const float* wrow = Wr + (size_t)h4 * 4 * E;
        float xs[4] = {xv.x, xv.y, xv.z, xv.w};
#pragma unroll
        for (int j = 0; j < 4; j++)
#pragma unroll
          for (int e = 0; e < E; e++) acc[e] += xs[j] * wrow[j * E + e];
      }
#pragma unroll
      for (int e = 0; e < E; e++) {
        float v = acc[e];
        for (int off = 32; off > 0; off >>= 1) v += __shfl_down(v, off, 64);
        acc[e] = v;
      }
      if (lane == 0) {
        float logits[E];
#pragma unroll
        for (int e = 0; e < E; e++) logits[e] = acc[e] + br[e];
        int i0 = 0;
        float v0 = logits[0];
#pragma unroll
        for (int e = 1; e < E; e++)
          if (logits[e] > v0) { v0 = logits[e]; i0 = e; }
        int i1 = -1;
        float v1 = -INFINITY;
#pragma unroll
        for (int e = 0; e < E; e++) {
          if (e == i0) continue;
          if (logits[e] > v1) { v1 = logits[e]; i1 = e; }
        }
        float s1 = __expf(v1 - v0);
        float denom = 1.0f + s1;
        int p0 = atomicAdd(&cnt_s[i0], 1);
        tok_e[i0][p0] = t * 2 + 0;       // slot 0
        wv_e[i0][p0] = 1.0f / denom;
        int p1 = atomicAdd(&cnt_s[i1], 1);
        tok_e[i1][p1] = t * 2 + 1;       // slot 1
        wv_e[i1][p1] = s1 / denom;
      }
    }
    __syncthreads();
    if (tid < E) base_s[tid] = atomicAdd(&e_cnt[tid], cnt_s[tid]);
    __syncthreads();
#pragma unroll
    for (int e = 0; e < E; e++) {
      int c = cnt_s[e], b0 = base_s[e];
      for (int j = tid; j < c; j += 256) {
        row_token[e * CAP + b0 + j] = tok_e[e][j];
        row_w[e * CAP + b0 + j] = wv_e[e][j];
      }
    }
    return;
  }

  __shared__ float tile[64][65];
  int q = bid - RTR_BLKS;
  if (q < WGU_TILES) {
    int e = q / 288, rem = q % 288;
    int n0 = (rem % 24) * 64;
    int k0 = (rem / 24) * 64;
    transpose_tile(Wgu + (size_t)e * H * TWO_I, Wgt + (size_t)e * TWO_I * H,
                   TWO_I, n0, k0, tile, tid);
  } else {
    int q2 = q - WGU_TILES;
    int e = q2 / 144, rem = q2 % 144;
    int n0 = (rem % 12) * 64;
    int k0 = (rem / 12) * 64;
    transpose_tile(Wd + (size_t)e * H * I, Wdt + (size_t)e * H * I,
                   H, n0, k0, tile, tid);
  }
}

// ---------------------------------------------------------------------------
// GEMM1: 128m x 64n gate+up, K=768, BK=64, XOR swizzle, 2-stage dbuf,
// vmcnt(8). bid%8 XCD affinity. (R8-proven inner loop, byte-identical;
// Wd-transpose blocks removed — they live in pre now.)
// ---------------------------------------------------------------------------
__global__ __launch_bounds__(256) void gemm_gu_mfma(
    const unsigned short* __restrict__ xb, const unsigned short* __restrict__ Wgt,
    const float* __restrict__ bgu, const int* __restrict__ e_cnt,
    const int* __restrict__ row_token, unsigned short* __restrict__ act) {
  __shared__ short As[2][128 * 64];
  __shared__ short Bg[2][64 * 64];
  __shared__ short Bu[2][64 * 64];
  __shared__ int tok[128];
  int bid = blockIdx.x;
  int tid = threadIdx.x;

  int g = bid % (E * NT1);       // (e*12 + n), fixed XCD = g%8
  int mt = bid / (E * NT1);
  int e = g / NT1;
  int n0 = (g % NT1) * 64;
  int cnt = e_cnt[e];
  int m0 = mt * 128;
  if (m0 >= cnt) return;
  int start = e * CAP;
  const unsigned short* Wg = Wgt + (size_t)e * TWO_I * H;  // [f][h]
  const float* bias = bgu + (size_t)e * TWO_I;

  if (tid < 128) {
    int m = m0 + tid;
    tok[tid] = row_token[start + ((m < cnt) ? m : (cnt - 1))];
  }
  __syncthreads();

  int lane = tid & 63;
  int wave = tid >> 6;
  int quad = lane >> 4;
  int lrow = lane & 15;
  int wm = (wave >> 1) * 64;
  int wn = (wave & 1) * 32;

  const unsigned short* gA[4];
  int oA[4];
#pragma unroll
  for (int r = 0; r < 4; r++) {
    int s = (wave * 4 + r) * 64 + lane;
    int row = s >> 3;
    int gg = (s & 7) ^ (row & 7);
    gA[r] = xb + (size_t)(tok[row] >> 1) * H + gg * 8;
    oA[r] = (wave * 4 + r) * 64 * 8;
  }
  const unsigned short *gBg[2], *gBu[2];
  int oB[2];
#pragma unroll
  for (int r = 0; r < 2; r++) {
    int s = (wave * 2 + r) * 64 + lane;
    int row = s >> 3;
    int gg = (s & 7) ^ (row & 7);
    gBg[r] = Wg + (size_t)(n0 + row) * H + gg * 8;
    gBu[r] = gBg[r] + (size_t)I * H;
    oB[r] = (wave * 2 + r) * 64 * 8;
  }

  float bgv[2], buv[2];
#pragma unroll
  for (int tj = 0; tj < 2; tj++) {
    int ncol = n0 + wn + tj * 16 + lrow;
    bgv[tj] = bias[ncol];
    buv[tj] = bias[I + ncol];
  }

  floatx4 accg[4][2], accu[4][2];
#pragma unroll
  for (int i = 0; i < 4; i++)
#pragma unroll
    for (int j = 0; j < 2; j++) {
      accg[i][j] = floatx4{0.f, 0.f, 0.f, 0.f};
      accu[i][j] = floatx4{0.f, 0.f, 0.f, 0.f};
    }

  __syncthreads();  // drain so in-loop vmcnt sees only staging DMAs

#pragma unroll
  for (int r = 0; r < 4; r++) g2l16(gA[r], &As[0][oA[r]]);
#pragma unroll
  for (int r = 0; r < 2; r++) {
    g2l16(gBg[r], &Bg[0][oB[r]]);
    g2l16(gBu[r], &Bu[0][oB[r]]);
  }

  constexpr int NK = H / 64;  // 12
  for (int i = 0; i < NK; i++) {
    int cb = i & 1;
    if (i + 1 < NK) {
      int nb = cb ^ 1;
      int k1 = (i + 1) * 64;
#pragma unroll
      for (int r = 0; r < 4; r++) g2l16(gA[r] + k1, &As[nb][oA[r]]);
#pragma unroll
      for (int r = 0; r < 2; r++) {
        g2l16(gBg[r] + k1, &Bg[nb][oB[r]]);
        g2l16(gBu[r] + k1, &Bu[nb][oB[r]]);
      }
      asm volatile("s_waitcnt vmcnt(8)" ::: "memory");
    } else {
      asm volatile("s_waitcnt vmcnt(0)" ::: "memory");
    }
    __builtin_amdgcn_s_barrier();

#pragma unroll
    for (int ks = 0; ks < 2; ks++) {
      int c = ks * 4 + quad;
      short8 a[4], bg[2], bu[2];
#pragma unroll
      for (int ti = 0; ti < 4; ti++) {
        int r = wm + ti * 16 + lrow;
        a[ti] = *(const short8*)(&As[cb][(r * 8 + (c ^ (r & 7))) * 8]);
      }
#pragma unroll
      for (int tj = 0; tj < 2; tj++) {
        int r = wn + tj * 16 + lrow;
        bg[tj] = *(const short8*)(&Bg[cb][(r * 8 + (c ^ (r & 7))) * 8]);
        bu[tj] = *(const short8*)(&Bu[cb][(r * 8 + (c ^ (r & 7))) * 8]);
      }
#pragma unroll
      for (int ti = 0; ti < 4; ti++)
#pragma unroll
        for (int tj = 0; tj < 2; tj++) {
          accg[ti][tj] = __builtin_amdgcn_mfma_f32_16x16x32_bf16(
              a[ti], bg[tj], accg[ti][tj], 0, 0, 0);
          accu[ti][tj] = __builtin_amdgcn_mfma_f32_16x16x32_bf16(
              a[ti], bu[tj], accu[ti][tj], 0, 0, 0);
        }
    }
    __builtin_amdgcn_s_barrier();  // reads of cb done before refill
  }

#pragma unroll
  for (int ti = 0; ti < 4; ti++) {
#pragma unroll
    for (int tj = 0; tj < 2; tj++) {
      int ncol = n0 + wn + tj * 16 + lrow;
#pragma unroll
      for (int r = 0; r < 4; r++) {
        int m = m0 + wm + ti * 16 + quad * 4 + r;
        if (m < cnt) {
          float gg = accg[ti][tj][r] + bgv[tj];
          float u = accu[ti][tj][r] + buv[tj];
          gg = fminf(gg, LIMIT);
          u = fmaxf(fminf(u, LIMIT), -LIMIT);
          float glu = gg / (1.0f + __expf(-ALPHA * gg));
          act[(size_t)(start + m) * I + ncol] = f2bf((u + 1.0f) * glu);
        }
      }
    }
  }
}

// ---------------------------------------------------------------------------
// GEMM2 with SPLIT-K=2: each block computes a K-half (384) partial of
// down[t][slot] into down[t*4 + slot*2 + kp][H] via plain stores. Live
// blocks double (1.5 -> 3 per CU) and the serial K-chain halves (12 -> 6
// latency-exposed iterations). Inner loop byte-identical to R8; only the
// grid decode, K base offset, bias term and store row change.
// ---------------------------------------------------------------------------
__global__ __launch_bounds__(256) void gemm_down_mfma(
    const unsigned short* __restrict__ act, const unsigned short* __restrict__ Wdt,
    const float* __restrict__ bd, const int* __restrict__ e_cnt,
    const int* __restrict__ row_token, const float* __restrict__ row_w,
    float* __restrict__ down) {
  __shared__ short As[2][128 * 64];
  __shared__ short Bs[2][64 * 64];
  __shared__ int tok[128];
  __shared__ float wts[128];
  int bid = blockIdx.x;
  int tid = threadIdx.x;

  int g = bid % (E * NT2);       // (e*12 + n), fixed XCD = g%8
  int q = bid / (E * NT2);       // 0..31
  int kp = q & 1;                // K-half
  int mt = q >> 1;               // 0..15
  int e = g / NT2;
  int n0 = (g % NT2) * 64;
  int cnt = e_cnt[e];
  int m0 = mt * 128;
  if (m0 >= cnt) return;
  int start = e * CAP;
  int k_off = kp * KH;           // 0 or 384
  const unsigned short* Wd = Wdt + (size_t)e * H * I;  // [h][i]
  const float* bias = bd + (size_t)e * H;

  if (tid < 128) {
    int m = m0 + tid;
    int mm = (m < cnt) ? m : (cnt - 1);
    tok[tid] = row_token[start + mm];
    wts[tid] = row_w[start + mm];
  }
  __syncthreads();

  int lane = tid & 63;
  int wave = tid >> 6;
  int quad = lane >> 4;
  int lrow = lane & 15;
  int wm = (wave >> 1) * 64;
  int wn = (wave & 1) * 32;

  const unsigned short* gA[4];
  int oA[4];
#pragma unroll
  for (int r = 0; r < 4; r++) {
    int s = (wave * 4 + r) * 64 + lane;
    int row = s >> 3;
    int gg = (s & 7) ^ (row & 7);
    int gm = m0 + row;
    int mm = (gm < cnt) ? gm : (cnt - 1);
    gA[r] = act + (size_t)(start + mm) * I + k_off + gg * 8;
    oA[r] = (wave * 4 + r) * 64 * 8;
  }
  const unsigned short* gB[2];
  int oB[2];
#pragma unroll
  for (int r = 0; r < 2; r++) {
    int s = (wave * 2 + r) * 64 + lane;
    int row = s >> 3;
    int gg = (s & 7) ^ (row & 7);
    gB[r] = Wd + (size_t)(n0 + row) * I + k_off + gg * 8;
    oB[r] = (wave * 2 + r) * 64 * 8;
  }

  float bdv[2];
#pragma unroll
  for (int tj = 0; tj < 2; tj++)
    bdv[tj] = kp ? 0.0f : bias[n0 + wn + tj * 16 + lrow];

  floatx4 acc[4][2];
#pragma unroll
  for (int i = 0; i < 4; i++)
#pragma unroll
    for (int j = 0; j < 2; j++) acc[i][j] = floatx4{0.f, 0.f, 0.f, 0.f};

  __syncthreads();  // drain; in-loop vmcnt sees only the 6 staging DMAs

#pragma unroll
  for (int r = 0; r < 4; r++) g2l16(gA[r], &As[0][oA[r]]);
#pragma unroll
  for (int r = 0; r < 2; r++) g2l16(gB[r], &Bs[0][oB[r]]);

  constexpr int NK = KH / 64;  // 6
  for (int i = 0; i < NK; i++) {
    int cb = i & 1;
    if (i + 1 < NK) {
      int nb = cb ^ 1;
      int k1 = (i + 1) * 64;
#pragma unroll
      for (int r = 0; r < 4; r++) g2l16(gA[r] + k1, &As[nb][oA[r]]);
#pragma unroll
      for (int r = 0; r < 2; r++) g2l16(gB[r] + k1, &Bs[nb][oB[r]]);
      asm volatile("s_waitcnt vmcnt(6)" ::: "memory");
    } else {
      asm volatile("s_waitcnt vmcnt(0)" ::: "memory");
    }
    __builtin_amdgcn_s_barrier();

#pragma unroll
    for (int ks = 0; ks < 2; ks++) {
      int c = ks * 4 + quad;
      short8 a[4], b[2];
#pragma unroll
      for (int ti = 0; ti < 4; ti++) {
        int r = wm + ti * 16 + lrow;
        a[ti] = *(const short8*)(&As[cb][(r * 8 + (c ^ (r & 7))) * 8]);
      }
#pragma unroll
      for (int tj = 0; tj < 2; tj++) {
        int r = wn + tj * 16 + lrow;
        b[tj] = *(const short8*)(&Bs[cb][(r * 8 + (c ^ (r & 7))) * 8]);
      }
#pragma unroll
      for (int ti = 0; ti < 4; ti++)
#pragma unroll
        for (int tj = 0; tj < 2; tj++)
          acc[ti][tj] = __builtin_amdgcn_mfma_f32_16x16x32_bf16(
              a[ti], b[tj], acc[ti][tj], 0, 0, 0);
    }
    __builtin_amdgcn_s_barrier();
  }

#pragma unroll
  for (int ti = 0; ti < 4; ti++) {
#pragma unroll
    for (int tj = 0; tj < 2; tj++) {
      int ncol = n0 + wn + tj * 16 + lrow;
#pragma unroll
      for (int r = 0; r < 4; r++) {
        int ml = wm + ti * 16 + quad * 4 + r;
        int m = m0 + ml;
        if (m < cnt) {
          // row = tok*2 + kp = t*4 + slot*2 + kp
          down[((size_t)tok[ml] * 2 + kp) * H + ncol] =
              wts[ml] * (acc[ti][tj][r] + bdv[tj]);
        }
      }
    }
  }
}

// ---------------------------------------------------------------------------
// Reduce: out[t][h] = sum of 4 partial rows (2 slots x 2 K-halves).
// ---------------------------------------------------------------------------
__global__ __launch_bounds__(256) void reduce_out(
    const float* __restrict__ down, float* __restrict__ out) {
  int i4 = blockIdx.x * 256 + threadIdx.x;  // 0 .. T*H/4-1
  int t = i4 / (H / 4);
  int c = i4 % (H / 4);
  const float* base = down + (size_t)(4 * t) * H;
  float4 r0 = ((const float4*)(base + 0 * H))[c];
  float4 r1 = ((const float4*)(base + 1 * H))[c];
  float4 r2 = ((const float4*)(base + 2 * H))[c];
  float4 r3 = ((const float4*)(base + 3 * H))[c];
  float4 r = {r0.x + r1.x + r2.x + r3.x, r0.y + r1.y + r2.y + r3.y,
              r0.z + r1.z + r2.z + r3.z, r0.w + r1.w + r2.w + r3.w};
  ((float4*)(out + (size_t)t * H))[c] = r;
}

// ---------------------------------------------------------------------------
extern "C" void kernel_launch(void* const* d_in, const int* in_sizes, int n_in,
                              void* d_out, int out_size, void* d_ws,
                              size_t ws_size, hipStream_t stream) {
  const float* x   = (const float*)d_in[0];
  const float* Wr  = (const float*)d_in[1];
  const float* br  = (const float*)d_in[2];
  const float* Wgu = (const float*)d_in[3];
  const float* bgu = (const float*)d_in[4];
  const float* Wd  = (const float*)d_in[5];
  const float* bd  = (const float*)d_in[6];
  float* out = (float*)d_out;

  char* w = (char*)d_ws;
  int* e_cnt = (int*)w;       w += 16 * sizeof(int);
  int* row_token = (int*)w;   w += (size_t)E * CAP * sizeof(int);
  float* row_w = (float*)w;   w += (size_t)E * CAP * sizeof(float);
  unsigned short* xb  = (unsigned short*)w; w += (size_t)T * H * 2;         // 3.1 MB
  unsigned short* Wgt = (unsigned short*)w; w += (size_t)E * TWO_I * H * 2; // 18.9 MB
  unsigned short* Wdt = (unsigned short*)w; w += (size_t)E * H * I * 2;     // 9.4 MB
  unsigned short* act = (unsigned short*)w; w += (size_t)E * CAP * I * 2;   // 25.2 MB
  float* down = (float*)w;    w += (size_t)T * 4 * H * sizeof(float);       // 25.2 MB

  hipMemsetAsync(e_cnt, 0, 16 * sizeof(int), stream);
  pre_all<<<PRE_BLKS, 256, 0, stream>>>(
      x, Wr, br, Wgu, Wd, Wgt, Wdt, xb, e_cnt, row_token, row_w);
  gemm_gu_mfma<<<G1_BLKS, 256, 0, stream>>>(
      xb, Wgt, bgu, e_cnt, row_token, act);
  gemm_down_mfma<<<G2_BLKS, 256, 0, stream>>>(
      act, Wdt, bd, e_cnt, row_token, row_w, down);
  reduce_out<<<RED_BLKS, 256, 0, stream>>>(down, out);
}

// Round 11
// 160.846 us; speedup vs baseline: 1.2982x; 1.0061x over previous
//
#include <hip/hip_runtime.h>
#include <hip/hip_bf16.h>
#include <cmath>

#define ALPHA 1.702f
#define LIMIT 7.0f

constexpr int B = 2, S = 1024, H = 768, E = 8, I = 768;
constexpr int T = B * S;          // 2048 tokens
constexpr int TWO_I = 2 * I;      // 1536
constexpr int CAP = T;            // per-expert row capacity
constexpr int NT1 = I / 64;       // 12 n-tiles (gemm1)
constexpr int NT2 = H / 64;       // 12 n-tiles (gemm2)
constexpr int MT = CAP / 128;     // 16 m-tiles

constexpr int RTR_BLKS = 64;
constexpr int WGU_TILES = E * (TWO_I / 64) * (H / 64);  // 2304
constexpr int WD_TILES  = E * (H / 64) * (H / 64);      // 1152
constexpr int PRE_BLKS = RTR_BLKS + WGU_TILES;          // 2368
constexpr int G1_BLKS = MT * E * NT1;                   // 1536
constexpr int K1_BLKS = G1_BLKS + WD_TILES;             // 2688
constexpr int G2_BLKS = MT * E * NT2;                   // 1536
constexpr int RED_BLKS = (T * H / 4) / 256;             // 1536

typedef __attribute__((ext_vector_type(8))) short short8;
typedef __attribute__((ext_vector_type(4))) float floatx4;

__device__ __forceinline__ unsigned short f2bf(float v) {
  __hip_bfloat16 h = __float2bfloat16(v);
  return *reinterpret_cast<unsigned short*>(&h);
}

// async global->LDS, 16B per lane. LDS dst is wave-uniform base + lane*16.
__device__ __forceinline__ void g2l16(const void* g, void* l) {
  __builtin_amdgcn_global_load_lds(
      (const __attribute__((address_space(1))) void*)g,
      (__attribute__((address_space(3))) void*)l, 16, 0, 0);
}

// 64x64 fp32->bf16 transpose tile via LDS (R1-proven body).
__device__ __forceinline__ void transpose_tile(
    const float* __restrict__ in, unsigned short* __restrict__ outw,
    int N, int n0, int k0, float (*tile)[65], int tid) {
  constexpr int K = 768;
  int jr = tid & 15, r0 = tid >> 4;
#pragma unroll
  for (int p = 0; p < 4; p++) {
    int k = r0 + p * 16;
    float4 v = *(const float4*)(in + (size_t)(k0 + k) * N + n0 + jr * 4);
    tile[k][jr * 4 + 0] = v.x;
    tile[k][jr * 4 + 1] = v.y;
    tile[k][jr * 4 + 2] = v.z;
    tile[k][jr * 4 + 3] = v.w;
  }
  __syncthreads();
#pragma unroll
  for (int p = 0; p < 4; p++) {
    int n = r0 + p * 16;
    ushort4 o;
    o.x = f2bf(tile[jr * 4 + 0][n]);
    o.y = f2bf(tile[jr * 4 + 1][n]);
    o.z = f2bf(tile[jr * 4 + 2][n]);
    o.w = f2bf(tile[jr * 4 + 3][n]);
    *(ushort4*)(outw + (size_t)(n0 + n) * K + k0 + jr * 4) = o;
  }
}

// ---------------------------------------------------------------------------
// K0: router (+assignment, xb cast) and Wgu transpose in ONE launch.
// row_token encodes t*2+slot (slot 0 = top1, 1 = top2) so gemm2 can
// scatter into a dense [t][slot][H] buffer with plain stores (no atomics).
// ---------------------------------------------------------------------------
__global__ __launch_bounds__(256) void pre_router_wgu(
    const float* __restrict__ x, const float* __restrict__ Wr,
    const float* __restrict__ br, const float* __restrict__ Wgu,
    unsigned short* __restrict__ Wgt, unsigned short* __restrict__ xb,
    int* __restrict__ e_cnt, int* __restrict__ row_token,
    float* __restrict__ row_w) {
  int bid = blockIdx.x;
  int tid = threadIdx.x;

  if (bid < RTR_BLKS) {
    __shared__ int cnt_s[E];
    __shared__ int base_s[E];
    __shared__ int tok_e[E][64];
    __shared__ float wv_e[E][64];

    if (tid < E) cnt_s[tid] = 0;
    __syncthreads();

    int wave = tid >> 6;
    int lane = tid & 63;

    for (int tt = 0; tt < 8; tt++) {
      int t = bid * 32 + wave * 8 + tt;
      const float* xr = x + (size_t)t * H;

      float acc[E];
#pragma unroll
      for (int e = 0; e < E; e++) acc[e] = 0.0f;

#pragma unroll
      for (int it = 0; it < 3; it++) {
        int h4 = it * 64 + lane;
        float4 xv = *(const float4*)(xr + (size_t)h4 * 4);
        ushort4 xo;
        xo.x = f2bf(xv.x);
        xo.y = f2bf(xv.y);
        xo.z = f2bf(xv.z);
        xo.w = f2bf(xv.w);
        *(ushort4*)(xb + (size_t)t * H + (size_t)h4 * 4) = xo;
        const float* wrow = Wr + (size_t)h4 * 4 * E;
        float xs[4] = {xv.x, xv.y, xv.z, xv.w};
#pragma unroll
        for (int j = 0; j < 4; j++)
#pragma unroll
          for (int e = 0; e < E; e++) acc[e] += xs[j] * wrow[j * E + e];
      }
#pragma unroll
      for (int e = 0; e < E; e++) {
        float v = acc[e];
        for (int off = 32; off > 0; off >>= 1) v += __shfl_down(v, off, 64);
        acc[e] = v;
      }
      if (lane == 0) {
        float logits[E];
#pragma unroll
        for (int e = 0; e < E; e++) logits[e] = acc[e] + br[e];
        int i0 = 0;
        float v0 = logits[0];
#pragma unroll
        for (int e = 1; e < E; e++)
          if (logits[e] > v0) { v0 = logits[e]; i0 = e; }
        int i1 = -1;
        float v1 = -INFINITY;
#pragma unroll
        for (int e = 0; e < E; e++) {
          if (e == i0) continue;
          if (logits[e] > v1) { v1 = logits[e]; i1 = e; }
        }
        float s1 = __expf(v1 - v0);
        float denom = 1.0f + s1;
        int p0 = atomicAdd(&cnt_s[i0], 1);
        tok_e[i0][p0] = t * 2 + 0;       // slot 0
        wv_e[i0][p0] = 1.0f / denom;
        int p1 = atomicAdd(&cnt_s[i1], 1);
        tok_e[i1][p1] = t * 2 + 1;       // slot 1
        wv_e[i1][p1] = s1 / denom;
      }
    }
    __syncthreads();
    if (tid < E) base_s[tid] = atomicAdd(&e_cnt[tid], cnt_s[tid]);
    __syncthreads();
#pragma unroll
    for (int e = 0; e < E; e++) {
      int c = cnt_s[e], b0 = base_s[e];
      for (int j = tid; j < c; j += 256) {
        row_token[e * CAP + b0 + j] = tok_e[e][j];
        row_w[e * CAP + b0 + j] = wv_e[e][j];
      }
    }
    return;
  }

  // Wgu transpose tiles
  __shared__ float tile[64][65];
  int q = bid - RTR_BLKS;
  int e = q / 288, rem = q % 288;
  int n0 = (rem % 24) * 64;
  int k0 = (rem / 24) * 64;
  transpose_tile(Wgu + (size_t)e * H * TWO_I, Wgt + (size_t)e * TWO_I * H,
                 TWO_I, n0, k0, tile, tid);
}

// ---------------------------------------------------------------------------
// K1: gemm1 (bid < 1536, proven 128m x 64n 2-stage BK=64 template, bid%8
// XCD affinity) + 1152 Wd-transpose blocks appended (proven overlap).
// ---------------------------------------------------------------------------
struct G1Smem {
  short As[2][128 * 64];
  short Bg[2][64 * 64];
  short Bu[2][64 * 64];
  int tok[128];
};
struct TSmem {
  float tile[64][65];
};

__global__ __launch_bounds__(256) void gemm_gu_wdT(
    const unsigned short* __restrict__ xb, const unsigned short* __restrict__ Wgt,
    const float* __restrict__ bgu, const int* __restrict__ e_cnt,
    const int* __restrict__ row_token, unsigned short* __restrict__ act,
    const float* __restrict__ Wd, unsigned short* __restrict__ Wdt) {
  __shared__ __align__(16) char smem_raw[sizeof(G1Smem)];
  int bid = blockIdx.x;
  int tid = threadIdx.x;

  if (bid >= G1_BLKS) {
    // ------------------- Wd transpose tile -------------------
    TSmem* ts = (TSmem*)smem_raw;
    int q = bid - G1_BLKS;
    int e = q / 144, rem = q % 144;
    int n0 = (rem % 12) * 64;
    int k0 = (rem / 12) * 64;
    transpose_tile(Wd + (size_t)e * H * I, Wdt + (size_t)e * H * I,
                   H, n0, k0, ts->tile, tid);
    return;
  }

  // ------------------- gemm1 -------------------
  G1Smem* sm = (G1Smem*)smem_raw;
  int g = bid % (E * NT1);       // (e*12 + n), fixed XCD = g%8
  int mt = bid / (E * NT1);      // m-tile
  int e = g / NT1;
  int n0 = (g % NT1) * 64;
  int cnt = e_cnt[e];
  int m0 = mt * 128;
  if (m0 >= cnt) return;
  int start = e * CAP;
  const unsigned short* Wg = Wgt + (size_t)e * TWO_I * H;  // [f][h]
  const float* bias = bgu + (size_t)e * TWO_I;

  if (tid < 128) {
    int m = m0 + tid;
    sm->tok[tid] = row_token[start + ((m < cnt) ? m : (cnt - 1))];
  }
  __syncthreads();

  int lane = tid & 63;
  int wave = tid >> 6;
  int quad = lane >> 4;
  int lrow = lane & 15;
  int wm = (wave >> 1) * 64;
  int wn = (wave & 1) * 32;

  const unsigned short* gA[4];
  int oA[4];
#pragma unroll
  for (int r = 0; r < 4; r++) {
    int s = (wave * 4 + r) * 64 + lane;
    int row = s >> 3;
    int gg = (s & 7) ^ (row & 7);
    gA[r] = xb + (size_t)(sm->tok[row] >> 1) * H + gg * 8;
    oA[r] = (wave * 4 + r) * 64 * 8;
  }
  const unsigned short *gBg[2], *gBu[2];
  int oB[2];
#pragma unroll
  for (int r = 0; r < 2; r++) {
    int s = (wave * 2 + r) * 64 + lane;
    int row = s >> 3;
    int gg = (s & 7) ^ (row & 7);
    gBg[r] = Wg + (size_t)(n0 + row) * H + gg * 8;
    gBu[r] = gBg[r] + (size_t)I * H;
    oB[r] = (wave * 2 + r) * 64 * 8;
  }

  float bgv[2], buv[2];
#pragma unroll
  for (int tj = 0; tj < 2; tj++) {
    int ncol = n0 + wn + tj * 16 + lrow;
    bgv[tj] = bias[ncol];
    buv[tj] = bias[I + ncol];
  }

  floatx4 accg[4][2], accu[4][2];
#pragma unroll
  for (int i = 0; i < 4; i++)
#pragma unroll
    for (int j = 0; j < 2; j++) {
      accg[i][j] = floatx4{0.f, 0.f, 0.f, 0.f};
      accu[i][j] = floatx4{0.f, 0.f, 0.f, 0.f};
    }

  __syncthreads();  // drain so in-loop vmcnt sees only staging DMAs

#pragma unroll
  for (int r = 0; r < 4; r++) g2l16(gA[r], &sm->As[0][oA[r]]);
#pragma unroll
  for (int r = 0; r < 2; r++) {
    g2l16(gBg[r], &sm->Bg[0][oB[r]]);
    g2l16(gBu[r], &sm->Bu[0][oB[r]]);
  }

  constexpr int NK = H / 64;  // 12
  for (int i = 0; i < NK; i++) {
    int cb = i & 1;
    if (i + 1 < NK) {
      int nb = cb ^ 1;
      int k1 = (i + 1) * 64;
#pragma unroll
      for (int r = 0; r < 4; r++) g2l16(gA[r] + k1, &sm->As[nb][oA[r]]);
#pragma unroll
      for (int r = 0; r < 2; r++) {
        g2l16(gBg[r] + k1, &sm->Bg[nb][oB[r]]);
        g2l16(gBu[r] + k1, &sm->Bu[nb][oB[r]]);
      }
      asm volatile("s_waitcnt vmcnt(8)" ::: "memory");
    } else {
      asm volatile("s_waitcnt vmcnt(0)" ::: "memory");
    }
    __builtin_amdgcn_s_barrier();

#pragma unroll
    for (int ks = 0; ks < 2; ks++) {
      int c = ks * 4 + quad;
      short8 a[4], bg[2], bu[2];
#pragma unroll
      for (int ti = 0; ti < 4; ti++) {
        int r = wm + ti * 16 + lrow;
        a[ti] = *(const short8*)(&sm->As[cb][(r * 8 + (c ^ (r & 7))) * 8]);
      }
#pragma unroll
      for (int tj = 0; tj < 2; tj++) {
        int r = wn + tj * 16 + lrow;
        bg[tj] = *(const short8*)(&sm->Bg[cb][(r * 8 + (c ^ (r & 7))) * 8]);
        bu[tj] = *(const short8*)(&sm->Bu[cb][(r * 8 + (c ^ (r & 7))) * 8]);
      }
#pragma unroll
      for (int ti = 0; ti < 4; ti++)
#pragma unroll
        for (int tj = 0; tj < 2; tj++) {
          accg[ti][tj] = __builtin_amdgcn_mfma_f32_16x16x32_bf16(
              a[ti], bg[tj], accg[ti][tj], 0, 0, 0);
          accu[ti][tj] = __builtin_amdgcn_mfma_f32_16x16x32_bf16(
              a[ti], bu[tj], accu[ti][tj], 0, 0, 0);
        }
    }
    __builtin_amdgcn_s_barrier();  // reads of cb done before refill
  }

#pragma unroll
  for (int ti = 0; ti < 4; ti++) {
#pragma unroll
    for (int tj = 0; tj < 2; tj++) {
      int ncol = n0 + wn + tj * 16 + lrow;
#pragma unroll
      for (int r = 0; r < 4; r++) {
        int m = m0 + wm + ti * 16 + quad * 4 + r;
        if (m < cnt) {
          float gg = accg[ti][tj][r] + bgv[tj];
          float u = accu[ti][tj][r] + buv[tj];
          gg = fminf(gg, LIMIT);
          u = fmaxf(fminf(u, LIMIT), -LIMIT);
          float glu = gg / (1.0f + __expf(-ALPHA * gg));
          act[(size_t)(start + m) * I + ncol] = f2bf((u + 1.0f) * glu);
        }
      }
    }
  }
}

// ---------------------------------------------------------------------------
// GEMM2: down = act @ Wd[e] (+bd), weighted; scatter via PLAIN STORES into
// dense down[t][slot][H] (each (t,slot,h) written exactly once). No atomics.
// ---------------------------------------------------------------------------
__global__ __launch_bounds__(256) void gemm_down_mfma(
    const unsigned short* __restrict__ act, const unsigned short* __restrict__ Wdt,
    const float* __restrict__ bd, const int* __restrict__ e_cnt,
    const int* __restrict__ row_token, const float* __restrict__ row_w,
    float* __restrict__ down) {
  int bid = blockIdx.x;
  int g = bid % (E * NT2);
  int mt = bid / (E * NT2);
  int e = g / NT2;
  int n0 = (g % NT2) * 64;
  int cnt = e_cnt[e];
  int m0 = mt * 128;
  if (m0 >= cnt) return;
  int start = e * CAP;
  const unsigned short* Wd = Wdt + (size_t)e * H * I;  // [h][i]
  const float* bias = bd + (size_t)e * H;

  __shared__ short As[2][128 * 64];  // 32 KB
  __shared__ short Bs[2][64 * 64];   // 16 KB
  __shared__ int tok[128];
  __shared__ float wts[128];

  int tid = threadIdx.x;
  if (tid < 128) {
    int m = m0 + tid;
    int mm = (m < cnt) ? m : (cnt - 1);
    tok[tid] = row_token[start + mm];
    wts[tid] = row_w[start + mm];
  }
  __syncthreads();

  int lane = tid & 63;
  int wave = tid >> 6;
  int quad = lane >> 4;
  int lrow = lane & 15;
  int wm = (wave >> 1) * 64;
  int wn = (wave & 1) * 32;

  const unsigned short* gA[4];
  int oA[4];
#pragma unroll
  for (int r = 0; r < 4; r++) {
    int s = (wave * 4 + r) * 64 + lane;
    int row = s >> 3;
    int gg = (s & 7) ^ (row & 7);
    int gm = m0 + row;
    int mm = (gm < cnt) ? gm : (cnt - 1);
    gA[r] = act + (size_t)(start + mm) * I + gg * 8;
    oA[r] = (wave * 4 + r) * 64 * 8;
  }
  const unsigned short* gB[2];
  int oB[2];
#pragma unroll
  for (int r = 0; r < 2; r++) {
    int s = (wave * 2 + r) * 64 + lane;
    int row = s >> 3;
    int gg = (s & 7) ^ (row & 7);
    gB[r] = Wd + (size_t)(n0 + row) * I + gg * 8;
    oB[r] = (wave * 2 + r) * 64 * 8;
  }

  float bdv[2];
#pragma unroll
  for (int tj = 0; tj < 2; tj++) bdv[tj] = bias[n0 + wn + tj * 16 + lrow];

  floatx4 acc[4][2];
#pragma unroll
  for (int i = 0; i < 4; i++)
#pragma unroll
    for (int j = 0; j < 2; j++) acc[i][j] = floatx4{0.f, 0.f, 0.f, 0.f};

  __syncthreads();  // drain; in-loop vmcnt sees only the 6 staging DMAs

#pragma unroll
  for (int r = 0; r < 4; r++) g2l16(gA[r], &As[0][oA[r]]);
#pragma unroll
  for (int r = 0; r < 2; r++) g2l16(gB[r], &Bs[0][oB[r]]);

  constexpr int NK = I / 64;  // 12
  for (int i = 0; i < NK; i++) {
    int cb = i & 1;
    if (i + 1 < NK) {
      int nb = cb ^ 1;
      int k1 = (i + 1) * 64;
#pragma unroll
      for (int r = 0; r < 4; r++) g2l16(gA[r] + k1, &As[nb][oA[r]]);
#pragma unroll
      for (int r = 0; r < 2; r++) g2l16(gB[r] + k1, &Bs[nb][oB[r]]);
      asm volatile("s_waitcnt vmcnt(6)" ::: "memory");
    } else {
      asm volatile("s_waitcnt vmcnt(0)" ::: "memory");
    }
    __builtin_amdgcn_s_barrier();

#pragma unroll
    for (int ks = 0; ks < 2; ks++) {
      int c = ks * 4 + quad;
      short8 a[4], b[2];
#pragma unroll
      for (int ti = 0; ti < 4; ti++) {
        int r = wm + ti * 16 + lrow;
        a[ti] = *(const short8*)(&As[cb][(r * 8 + (c ^ (r & 7))) * 8]);
      }
#pragma unroll
      for (int tj = 0; tj < 2; tj++) {
        int r = wn + tj * 16 + lrow;
        b[tj] = *(const short8*)(&Bs[cb][(r * 8 + (c ^ (r & 7))) * 8]);
      }
#pragma unroll
      for (int ti = 0; ti < 4; ti++)
#pragma unroll
        for (int tj = 0; tj < 2; tj++)
          acc[ti][tj] = __builtin_amdgcn_mfma_f32_16x16x32_bf16(
              a[ti], b[tj], acc[ti][tj], 0, 0, 0);
    }
    __builtin_amdgcn_s_barrier();
  }

#pragma unroll
  for (int ti = 0; ti < 4; ti++) {
#pragma unroll
    for (int tj = 0; tj < 2; tj++) {
      int ncol = n0 + wn + tj * 16 + lrow;
#pragma unroll
      for (int r = 0; r < 4; r++) {
        int ml = wm + ti * 16 + quad * 4 + r;
        int m = m0 + ml;
        if (m < cnt) {
          down[(size_t)tok[ml] * H + ncol] =
              wts[ml] * (acc[ti][tj][r] + bdv[tj]);
        }
      }
    }
  }
}

// ---------------------------------------------------------------------------
// Reduce: out[t][h] = down[t][0][h] + down[t][1][h]. One float4 per thread.
// ---------------------------------------------------------------------------
__global__ __launch_bounds__(256) void reduce_out(
    const float* __restrict__ down, float* __restrict__ out) {
  int i4 = blockIdx.x * 256 + threadIdx.x;  // 0 .. T*H/4-1
  int t = i4 / (H / 4);
  int c = i4 % (H / 4);
  const float4* d0 = (const float4*)(down + (size_t)(2 * t) * H) + c;
  const float4* d1 = (const float4*)(down + (size_t)(2 * t + 1) * H) + c;
  float4 a = *d0, b = *d1;
  float4 r = {a.x + b.x, a.y + b.y, a.z + b.z, a.w + b.w};
  ((float4*)(out + (size_t)t * H))[c] = r;
}

// ---------------------------------------------------------------------------
extern "C" void kernel_launch(void* const* d_in, const int* in_sizes, int n_in,
                              void* d_out, int out_size, void* d_ws,
                              size_t ws_size, hipStream_t stream) {
  const float* x   = (const float*)d_in[0];
  const float* Wr  = (const float*)d_in[1];
  const float* br  = (const float*)d_in[2];
  const float* Wgu = (const float*)d_in[3];
  const float* bgu = (const float*)d_in[4];
  const float* Wd  = (const float*)d_in[5];
  const float* bd  = (const float*)d_in[6];
  float* out = (float*)d_out;

  char* w = (char*)d_ws;
  int* e_cnt = (int*)w;       w += 16 * sizeof(int);
  int* row_token = (int*)w;   w += (size_t)E * CAP * sizeof(int);
  float* row_w = (float*)w;   w += (size_t)E * CAP * sizeof(float);
  unsigned short* xb  = (unsigned short*)w; w += (size_t)T * H * 2;         // 3.1 MB
  unsigned short* Wgt = (unsigned short*)w; w += (size_t)E * TWO_I * H * 2; // 18.9 MB
  unsigned short* Wdt = (unsigned short*)w; w += (size_t)E * H * I * 2;     // 9.4 MB
  unsigned short* act = (unsigned short*)w; w += (size_t)E * CAP * I * 2;   // 25.2 MB
  float* down = (float*)w;    w += (size_t)T * 2 * H * sizeof(float);       // 12.6 MB

  hipMemsetAsync(e_cnt, 0, 16 * sizeof(int), stream);
  pre_router_wgu<<<PRE_BLKS, 256, 0, stream>>>(
      x, Wr, br, Wgu, Wgt, xb, e_cnt, row_token, row_w);
  gemm_gu_wdT<<<K1_BLKS, 256, 0, stream>>>(
      xb, Wgt, bgu, e_cnt, row_token, act, Wd, Wdt);
  gemm_down_mfma<<<G2_BLKS, 256, 0, stream>>>(
      act, Wdt, bd, e_cnt, row_token, row_w, down);
  reduce_out<<<RED_BLKS, 256, 0, stream>>>(down, out);
}